// Round 6
// baseline (227.578 us; speedup 1.0000x reference)
//
#include <hip/hip_runtime.h>

// ModulatedConv2d (StyleGAN2): B=8, Cin=Cout=512, k=3, H=W=64.
//   s[b,c]     = style @ (mod_weight/sqrt(512))^T + bias          (fp32)
//   scale[b,o] = cs * rsqrt(cs^2 * sum_c wsq[o,c]*s^2 + eps)
//   out[b,o,p] = scale[b,o] * sum_{c,k} w[o,c,k] * (s[b,c]*x[b,c,p'])
// k_conv v6: v5 skeleton (8 waves = 2/SIMD, 2x56KB dbuf, fragment-entry
// conflict-free LDS) + m201-style sub-phase schedule: per cc, 3 kx
// sub-phases {12 ds_read | stage | barrier | MFMA cluster | barrier}
// with setprio around MFMA. k_xt: register-blocked transpose (coalesced).

typedef __bf16 bf16x8 __attribute__((ext_vector_type(8)));
typedef float f32x16 __attribute__((ext_vector_type(16)));

#define AS1 __attribute__((address_space(1)))
#define AS3 __attribute__((address_space(3)))

__device__ __forceinline__ unsigned short f2bf(float f) {
  union { float f; unsigned int u; } v; v.f = f;
  unsigned int u = v.u;
  return (unsigned short)((u + 0x7fffu + ((u >> 16) & 1u)) >> 16);
}

__global__ void k_mod(const float* __restrict__ style, const float* __restrict__ mw,
                      const float* __restrict__ mb, float* __restrict__ s,
                      float* __restrict__ zp) {
  int t = blockIdx.x * 256 + threadIdx.x;   // 4096
  if (blockIdx.x == 0) {                    // 4KB zero page
    zp[threadIdx.x] = 0.f; zp[256 + threadIdx.x] = 0.f;
    zp[512 + threadIdx.x] = 0.f; zp[768 + threadIdx.x] = 0.f;
  }
  int b = t >> 9, c = t & 511;
  float acc = 0.f;
  for (int d = 0; d < 512; ++d) acc += style[b * 512 + d] * mw[c * 512 + d];
  s[t] = acc * 0.04419417382415922f + mb[c];  // 1/sqrt(512)
}

__global__ void k_wprep(const float* __restrict__ w, float* __restrict__ wsq,
                        unsigned short* __restrict__ wbf) {
  int t = blockIdx.x * 256 + threadIdx.x;   // 262144
  int o = t >> 9, c = t & 511;
  const float* wp = w + (size_t)(o * 512 + c) * 9;
  float q = 0.f;
#pragma unroll
  for (int k = 0; k < 9; ++k) {
    float v = wp[k];
    q += v * v;
    wbf[((size_t)k * 512 + o) * 512 + c] = f2bf(v);
  }
  wsq[t] = q;
}

__global__ void k_scale(const float* __restrict__ wsq, const float* __restrict__ s,
                        float* __restrict__ scale) {
  int t = blockIdx.x * 256 + threadIdx.x;   // 4096
  int b = t >> 9, o = t & 511;
  float acc = 0.f;
  for (int c = 0; c < 512; ++c) {
    float sv = s[b * 512 + c];
    acc += wsq[o * 512 + c] * sv * sv;
  }
  const float cs = 0.014731391274719739f;   // 1/sqrt(4608)
  scale[t] = cs * rsqrtf(cs * cs * acc + 1e-8f);
}

// xt[b][y][x][c] = bf16(s[b,c] * x[b,c,y,x]) — register-blocked 8c x 8x
// transpose per thread: coalesced float4 reads, 128B-segment 16B writes.
__global__ void k_xt(const float* __restrict__ x, const float* __restrict__ s,
                     unsigned short* __restrict__ xt) {
  int bid = blockIdx.x;            // 512 = b(8) * y(64)
  int b = bid >> 6, y = bid & 63;
  int t = threadIdx.x;             // 512
  int co = t >> 3, xo = t & 7;     // co 0..63 (8 c's), xo 0..7 (8 x's)
  const float* xbase = x + ((size_t)(b * 512 + co * 8) * 64 + y) * 64 + xo * 8;
  float4 v[8][2];
#pragma unroll
  for (int j = 0; j < 8; ++j) {
    v[j][0] = *(const float4*)(xbase + (size_t)j * 4096);
    v[j][1] = *(const float4*)(xbase + (size_t)j * 4096 + 4);
  }
  float sv[8];
#pragma unroll
  for (int j = 0; j < 8; ++j) sv[j] = s[b * 512 + co * 8 + j];
  unsigned short* obase =
      xt + ((size_t)(b * 64 + y) * 64 + xo * 8) * 512 + co * 8;
#pragma unroll
  for (int k = 0; k < 8; ++k) {
    unsigned short r[8];
#pragma unroll
    for (int j = 0; j < 8; ++j) {
      float f = (k < 4) ? ((const float*)&v[j][0])[k & 3]
                        : ((const float*)&v[j][1])[k & 3];
      r[j] = f2bf(f * sv[j]);
    }
    *(ulonglong2*)(obase + (size_t)k * 512) = *(ulonglong2*)r;
  }
}

// ---------------- k_conv v6 ----------------
// Block = 128o x 16y x 32x, 8 waves: wid = wyy(0..3)*2 + wo(0..1).
// Wave = 64o x (4y x 32x), acc[oh in 0..1][ry in 0..3], 8 f32x16 frags.
// Per 56KB buffer (56 issues x 1024B), entry = 16B = 8 c-values:
//   X: issues 0..19 : e = chunk(0..1)*612 + row(0..17)*34 + xi(0..33)
//      holds xt[yg*16+row-1][xg*32+xi-1][cc*16+chunk*8 ..+7]  (zp if OOB/pad)
//   W: issues 20..55: e2 = chunk*1152 + tap*128 + o(0..127)
//      holds wbf[tap][ob*128+o][cc*16+chunk*8 ..+7]
#define XISS 20
#define WOFF_US 10240    // 20 issues * 512 ushorts
#define BUFU    28672    // ushorts per buffer (57344 B)

__global__ __launch_bounds__(512, 2) void k_conv(
    const unsigned short* __restrict__ xt, const unsigned short* __restrict__ wbf,
    const float* __restrict__ scale, const float* __restrict__ zp,
    float* __restrict__ out) {
  __shared__ __align__(16) unsigned short lds[2 * BUFU];  // 114688 B

  int bid = blockIdx.x;            // 256 = 8 b * 4 ob * 4 yg * 2 xg
  int b = bid & 7;                 // XCD k owns batch b=k
  int rest = bid >> 3;
  int ob = rest & 3;
  int rest2 = rest >> 2;
  int yg = rest2 & 3;
  int xg = rest2 >> 2;

  int tid = threadIdx.x;
  int wid = tid >> 6;              // 0..7
  int wo = wid & 1, wyy = wid >> 1;
  int lane = tid & 63, ln31 = lane & 31, hi = lane >> 5;

  // ---- staging source pointers (7 issues per thread), advance 32B/phase ----
  const char* srcp[7];
  const char* xglob = (const char*)(xt + (size_t)b * 64 * 64 * 512);
#pragma unroll
  for (int i = 0; i < 7; ++i) {
    int is = wid + i * 8;          // 0..55
    const char* p;
    if (is < XISS) {
      int e = is * 64 + lane;
      int chunk = e / 612;
      int rem = e - chunk * 612;
      int row = rem / 34;
      int xi = rem - row * 34;
      int y = yg * 16 + row - 1, x = xg * 32 + xi - 1;
      bool ok = (chunk < 2) && (y >= 0) && (y < 64) && (x >= 0) && (x < 64);
      p = ok ? xglob + 2 * ((y * 64 + x) * 512 + chunk * 8) : (const char*)zp;
    } else {
      int e2 = (is - XISS) * 64 + lane;
      int chunk = e2 / 1152;
      int rem = e2 - chunk * 1152;
      int tap = rem >> 7, o = rem & 127;
      p = (const char*)wbf + 2 * ((tap * 512 + ob * 128 + o) * 512 + chunk * 8);
    }
    srcp[i] = p;
  }

  f32x16 acc[8];   // [oh*4 + ry]
#pragma unroll
  for (int i = 0; i < 8; ++i)
    acc[i] = (f32x16){0,0,0,0,0,0,0,0,0,0,0,0,0,0,0,0};

  auto STAGE = [&](int bufu) {
#pragma unroll
    for (int i = 0; i < 7; ++i) {
      __builtin_amdgcn_global_load_lds(
          (const AS1 void*)srcp[i],
          (AS3 void*)&lds[bufu + (wid + i * 8) * 512], 16, 0, 0);
      srcp[i] += 32;
    }
  };

  // One kx sub-phase: {12 ds_read | optional stage | bar | MFMA x24 | bar}
  auto SUB = [&](const unsigned short* Xbp, const unsigned short* Abp,
                 int kx, bool doStage, int stageBuf) {
    bf16x8 bv[6], av[6];
#pragma unroll
    for (int rr = 0; rr < 6; ++rr)
      bv[rr] = *(const bf16x8*)&Xbp[(rr * 34 + kx) * 8];
#pragma unroll
    for (int ky = 0; ky < 3; ++ky) {
      av[ky * 2]     = *(const bf16x8*)&Abp[(ky * 3 + kx) * 1024];
      av[ky * 2 + 1] = *(const bf16x8*)&Abp[(ky * 3 + kx) * 1024 + 256];
    }
    if (doStage) STAGE(stageBuf);
    __builtin_amdgcn_sched_barrier(0);
    __builtin_amdgcn_s_barrier();
    __builtin_amdgcn_sched_barrier(0);
    __builtin_amdgcn_s_setprio(1);
#pragma unroll
    for (int ky = 0; ky < 3; ++ky) {
#pragma unroll
      for (int ry = 0; ry < 4; ++ry) {
        acc[ry] = __builtin_amdgcn_mfma_f32_32x32x16_bf16(
            av[ky * 2], bv[ry + ky], acc[ry], 0, 0, 0);
        acc[4 + ry] = __builtin_amdgcn_mfma_f32_32x32x16_bf16(
            av[ky * 2 + 1], bv[ry + ky], acc[4 + ry], 0, 0, 0);
      }
    }
    __builtin_amdgcn_s_setprio(0);
    __builtin_amdgcn_sched_barrier(0);
  };

  // Full cc-phase: 3 kx sub-phases; staging of next buffer issued in sub0;
  // drain own stage loads before the final barrier (next phase reads them).
  auto PHASE = [&](const unsigned short* Xbp, const unsigned short* Abp,
                   int stageBuf, bool doStage) {
    SUB(Xbp, Abp, 0, doStage, stageBuf);
    __builtin_amdgcn_s_barrier();
    SUB(Xbp, Abp, 1, false, 0);
    __builtin_amdgcn_s_barrier();
    SUB(Xbp, Abp, 2, false, 0);
    asm volatile("s_waitcnt vmcnt(0)" ::: "memory");
    __builtin_amdgcn_s_barrier();
    __builtin_amdgcn_sched_barrier(0);
  };

  const unsigned short* Xb0 = &lds[(hi * 612 + wyy * 4 * 34 + ln31) * 8];
  const unsigned short* Ab0 = &lds[WOFF_US + (hi * 1152 + wo * 64 + ln31) * 8];
  const unsigned short* Xb1 = Xb0 + BUFU;
  const unsigned short* Ab1 = Ab0 + BUFU;

  STAGE(0);                                  // cc=0 -> buf0
  asm volatile("s_waitcnt vmcnt(0)" ::: "memory");
  __builtin_amdgcn_s_barrier();
  __builtin_amdgcn_sched_barrier(0);

#pragma unroll 1
  for (int t = 0; t < 16; ++t) {
    PHASE(Xb0, Ab0, BUFU, true);             // compute cc=2t, stage cc=2t+1
    PHASE(Xb1, Ab1, 0, t < 15);              // compute cc=2t+1, stage cc=2t+2
  }

  // ---- epilogue: C/D layout col=lane&31, row=(reg&3)+8*(reg>>2)+4*(lane>>5) ----
  const float* scp = scale + b * 512 + ob * 128 + wo * 64;
  float* op = out + (((size_t)(b * 512 + ob * 128 + wo * 64) * 64) +
                     yg * 16 + wyy * 4) * 64 + xg * 32 + ln31;
#pragma unroll
  for (int oh = 0; oh < 2; ++oh) {
#pragma unroll
    for (int ry = 0; ry < 4; ++ry) {
      const f32x16& A = acc[oh * 4 + ry];
#pragma unroll
      for (int reg = 0; reg < 16; ++reg) {
        int orow = (reg & 3) + 8 * (reg >> 2) + hi * 4;
        int ol = oh * 32 + orow;
        op[(size_t)ol * 4096 + ry * 64] = A[reg] * scp[ol];
      }
    }
  }
}

extern "C" void kernel_launch(void* const* d_in, const int* in_sizes, int n_in,
                              void* d_out, int out_size, void* d_ws, size_t ws_size,
                              hipStream_t stream) {
  const float* x     = (const float*)d_in[0];  // [8,512,64,64]
  const float* style = (const float*)d_in[1];  // [8,512]
  const float* w     = (const float*)d_in[2];  // [1,512,512,3,3]
  const float* mw    = (const float*)d_in[3];  // [512,512]
  const float* mb    = (const float*)d_in[4];  // [512]
  float* out = (float*)d_out;

  char* ws = (char*)d_ws;
  float* zp    = (float*)ws;                       // 4 KB zeros
  float* s     = (float*)(ws + 4096);              // 16 KB
  float* scale = (float*)(ws + 20480);             // 16 KB
  float* wsq   = (float*)(ws + 36864);             // 1 MB
  unsigned short* wbf = (unsigned short*)(ws + 1085440);   // 4.72 MB [9][512][512]
  unsigned short* xt  = (unsigned short*)(ws + 5804032);   // 33.5 MB [8][64][64][512]

  k_mod  <<<16,   256, 0, stream>>>(style, mw, mb, s, zp);
  k_wprep<<<1024, 256, 0, stream>>>(w, wsq, wbf);
  k_scale<<<16,   256, 0, stream>>>(wsq, s, scale);
  k_xt   <<<512,  512, 0, stream>>>(x, s, xt);
  k_conv <<<256,  512, 0, stream>>>(xt, wbf, scale, zp, out);
}

// Round 7
// 215.284 us; speedup vs baseline: 1.0571x; 1.0571x over previous
//
#include <hip/hip_runtime.h>

// ModulatedConv2d (StyleGAN2): B=8, Cin=Cout=512, k=3, H=W=64.
//   s[b,c]     = style @ (mod_weight/sqrt(512))^T + bias          (fp32)
//   scale[b,o] = cs * rsqrt(cs^2 * sum_c wsq[o,c]*s^2 + eps)
//   out[b,o,p] = scale[b,o] * sum_{c,k} w[o,c,k] * (s[b,c]*x[b,c,p'])
// k_conv v7 = v5 skeleton (8 waves = 2/SIMD, 2x56KB dbuf, fragment-entry
// conflict-free LDS, single drain+barrier per phase) + per-wave kx
// rotation: wave wid walks kx in order (wid%3, wid%3+1, wid%3+2)%3, so
// SIMD-paired waves sit in different read/MFMA stages -> pipes overlap
// without extra barriers. k_xt: LDS-transposed, 1KB-contiguous writes.

typedef __bf16 bf16x8 __attribute__((ext_vector_type(8)));
typedef float f32x16 __attribute__((ext_vector_type(16)));

#define AS1 __attribute__((address_space(1)))
#define AS3 __attribute__((address_space(3)))

__device__ __forceinline__ unsigned short f2bf(float f) {
  union { float f; unsigned int u; } v; v.f = f;
  unsigned int u = v.u;
  return (unsigned short)((u + 0x7fffu + ((u >> 16) & 1u)) >> 16);
}

__global__ void k_mod(const float* __restrict__ style, const float* __restrict__ mw,
                      const float* __restrict__ mb, float* __restrict__ s,
                      float* __restrict__ zp) {
  int t = blockIdx.x * 256 + threadIdx.x;   // 4096
  if (blockIdx.x == 0) {                    // 4KB zero page
    zp[threadIdx.x] = 0.f; zp[256 + threadIdx.x] = 0.f;
    zp[512 + threadIdx.x] = 0.f; zp[768 + threadIdx.x] = 0.f;
  }
  int b = t >> 9, c = t & 511;
  float acc = 0.f;
  for (int d = 0; d < 512; ++d) acc += style[b * 512 + d] * mw[c * 512 + d];
  s[t] = acc * 0.04419417382415922f + mb[c];  // 1/sqrt(512)
}

__global__ void k_wprep(const float* __restrict__ w, float* __restrict__ wsq,
                        unsigned short* __restrict__ wbf) {
  int t = blockIdx.x * 256 + threadIdx.x;   // 262144
  int o = t >> 9, c = t & 511;
  const float* wp = w + (size_t)(o * 512 + c) * 9;
  float q = 0.f;
#pragma unroll
  for (int k = 0; k < 9; ++k) {
    float v = wp[k];
    q += v * v;
    wbf[((size_t)k * 512 + o) * 512 + c] = f2bf(v);
  }
  wsq[t] = q;
}

__global__ void k_scale(const float* __restrict__ wsq, const float* __restrict__ s,
                        float* __restrict__ scale) {
  int t = blockIdx.x * 256 + threadIdx.x;   // 4096
  int b = t >> 9, o = t & 511;
  float acc = 0.f;
  for (int c = 0; c < 512; ++c) {
    float sv = s[b * 512 + c];
    acc += wsq[o * 512 + c] * sv * sv;
  }
  const float cs = 0.014731391274719739f;   // 1/sqrt(4608)
  scale[t] = cs * rsqrtf(cs * cs * acc + 1e-8f);
}

// xt[b][y][x][c] = bf16(s[b,c] * x[b,c,y,x]).
// Coalesced float4 reads; 8x8 per-thread block -> LDS (XOR-swizzled 16B
// slots, uniform bank residues) -> 1KB-contiguous wave writes.
__global__ void k_xt(const float* __restrict__ x, const float* __restrict__ s,
                     unsigned short* __restrict__ xt) {
  __shared__ __align__(16) unsigned short tile[64 * 65 * 8];  // 66560 B
  int bid = blockIdx.x;            // 512 = b(8) * y(64)
  int b = bid >> 6, y = bid & 63;
  int t = threadIdx.x;             // 512
  int co = t >> 3, xo = t & 7;     // co: c-octet 0..63, xo: x-octet 0..7
  const float* xbase = x + ((size_t)(b * 512 + co * 8) * 64 + y) * 64 + xo * 8;
  float4 v[8][2];
#pragma unroll
  for (int j = 0; j < 8; ++j) {
    v[j][0] = *(const float4*)(xbase + (size_t)j * 4096);
    v[j][1] = *(const float4*)(xbase + (size_t)j * 4096 + 4);
  }
  float sv[8];
#pragma unroll
  for (int j = 0; j < 8; ++j) sv[j] = s[b * 512 + co * 8 + j];
#pragma unroll
  for (int k = 0; k < 8; ++k) {
    unsigned short r[8];
#pragma unroll
    for (int j = 0; j < 8; ++j) {
      float f = (k < 4) ? ((const float*)&v[j][0])[k & 3]
                        : ((const float*)&v[j][1])[k & 3];
      r[j] = f2bf(f * sv[j]);
    }
    int xr = xo * 8 + k;
    int unit = xr * 65 + (co ^ xr);          // 16B-slot index, XOR swizzle
    *(ulonglong2*)&tile[unit * 8] = *(ulonglong2*)r;
  }
  __syncthreads();
  unsigned short* obase = xt + ((size_t)(b * 64 + y) * 64) * 512;
#pragma unroll
  for (int i = 0; i < 8; ++i) {
    int unit_o = i * 512 + t;                // output 16B-unit index
    int xr = unit_o >> 6, cor = unit_o & 63;
    int unit = xr * 65 + (cor ^ xr);
    *(ulonglong2*)&obase[(size_t)unit_o * 8] = *(const ulonglong2*)&tile[unit * 8];
  }
}

// ---------------- k_conv v7 ----------------
// Block = 128o x 16y x 32x, 8 waves: wid = wyy(0..3)*2 + wo(0..1).
// Wave = 64o x (4y x 32x), acc[oh in 0..1][ry in 0..3], 8 f32x16 frags.
// Per 56KB buffer (56 issues x 1024B), entry = 16B = 8 c-values:
//   X: issues 0..19 : e = chunk(0..1)*612 + row(0..17)*34 + xi(0..33)
//      holds xt[yg*16+row-1][xg*32+xi-1][cc*16+chunk*8 ..+7]  (zp if OOB/pad)
//   W: issues 20..55: e2 = chunk*1152 + tap*128 + o(0..127)
//      holds wbf[tap][ob*128+o][cc*16+chunk*8 ..+7]
#define XISS 20
#define WOFF_US 10240    // 20 issues * 512 ushorts
#define BUFU    28672    // ushorts per buffer (57344 B)

__global__ __launch_bounds__(512, 2) void k_conv(
    const unsigned short* __restrict__ xt, const unsigned short* __restrict__ wbf,
    const float* __restrict__ scale, const float* __restrict__ zp,
    float* __restrict__ out) {
  __shared__ __align__(16) unsigned short lds[2 * BUFU];  // 114688 B

  int bid = blockIdx.x;            // 256 = 8 b * 4 ob * 4 yg * 2 xg
  int b = bid & 7;                 // XCD k owns batch b=k
  int rest = bid >> 3;
  int ob = rest & 3;
  int rest2 = rest >> 2;
  int yg = rest2 & 3;
  int xg = rest2 >> 2;

  int tid = threadIdx.x;
  int wid = tid >> 6;              // 0..7
  int wo = wid & 1, wyy = wid >> 1;
  int lane = tid & 63, ln31 = lane & 31, hi = lane >> 5;
  int kxs = wid % 3;               // per-wave kx rotation start

  // ---- staging source pointers (7 issues per thread), advance 32B/phase ----
  const char* srcp[7];
  const char* xglob = (const char*)(xt + (size_t)b * 64 * 64 * 512);
#pragma unroll
  for (int i = 0; i < 7; ++i) {
    int is = wid + i * 8;          // 0..55
    const char* p;
    if (is < XISS) {
      int e = is * 64 + lane;
      int chunk = e / 612;
      int rem = e - chunk * 612;
      int row = rem / 34;
      int xi = rem - row * 34;
      int y = yg * 16 + row - 1, x = xg * 32 + xi - 1;
      bool ok = (chunk < 2) && (y >= 0) && (y < 64) && (x >= 0) && (x < 64);
      p = ok ? xglob + 2 * ((y * 64 + x) * 512 + chunk * 8) : (const char*)zp;
    } else {
      int e2 = (is - XISS) * 64 + lane;
      int chunk = e2 / 1152;
      int rem = e2 - chunk * 1152;
      int tap = rem >> 7, o = rem & 127;
      p = (const char*)wbf + 2 * ((tap * 512 + ob * 128 + o) * 512 + chunk * 8);
    }
    srcp[i] = p;
  }

  f32x16 acc[8];   // [oh*4 + ry]
#pragma unroll
  for (int i = 0; i < 8; ++i)
    acc[i] = (f32x16){0,0,0,0,0,0,0,0,0,0,0,0,0,0,0,0};

  auto STAGE = [&](int bufu) {
#pragma unroll
    for (int i = 0; i < 7; ++i) {
      __builtin_amdgcn_global_load_lds(
          (const AS1 void*)srcp[i],
          (AS3 void*)&lds[bufu + (wid + i * 8) * 512], 16, 0, 0);
      srcp[i] += 32;
    }
  };

  // Per-wave kx order: kxs, kxs+1, kxs+2 (mod 3). All kx sub-blocks read
  // the same read-only buffer -> reorder is trivially correct; SIMD-paired
  // waves (wid, wid+4) differ by 1 mod 3 -> read/MFMA windows interleave.
  auto COMPUTE = [&](const unsigned short* Xbp, const unsigned short* Abp) {
#pragma unroll
    for (int j = 0; j < 3; ++j) {
      int kx = kxs + j;
      if (kx >= 3) kx -= 3;
      const unsigned short* Xk = Xbp + kx * 8;       // +kx entries (16B each)
      const unsigned short* Ak = Abp + kx * 1024;    // +kx taps
      bf16x8 bv[6], av[6];
#pragma unroll
      for (int rr = 0; rr < 6; ++rr)
        bv[rr] = *(const bf16x8*)&Xk[rr * 272];      // rr*34 entries
#pragma unroll
      for (int ky = 0; ky < 3; ++ky) {
        av[ky * 2]     = *(const bf16x8*)&Ak[ky * 3072];
        av[ky * 2 + 1] = *(const bf16x8*)&Ak[ky * 3072 + 256];
      }
      __builtin_amdgcn_s_setprio(1);
#pragma unroll
      for (int ky = 0; ky < 3; ++ky) {
#pragma unroll
        for (int ry = 0; ry < 4; ++ry) {
          acc[ry] = __builtin_amdgcn_mfma_f32_32x32x16_bf16(
              av[ky * 2], bv[ry + ky], acc[ry], 0, 0, 0);
          acc[4 + ry] = __builtin_amdgcn_mfma_f32_32x32x16_bf16(
              av[ky * 2 + 1], bv[ry + ky], acc[4 + ry], 0, 0, 0);
        }
      }
      __builtin_amdgcn_s_setprio(0);
    }
  };

  const unsigned short* Xb0 = &lds[(hi * 612 + wyy * 4 * 34 + ln31) * 8];
  const unsigned short* Ab0 = &lds[WOFF_US + (hi * 1152 + wo * 64 + ln31) * 8];
  const unsigned short* Xb1 = Xb0 + BUFU;
  const unsigned short* Ab1 = Ab0 + BUFU;

  STAGE(0);                                  // cc=0 -> buf0
  asm volatile("s_waitcnt vmcnt(0) lgkmcnt(0)" ::: "memory");
  __builtin_amdgcn_s_barrier();
  __builtin_amdgcn_sched_barrier(0);

#pragma unroll 1
  for (int t = 0; t < 16; ++t) {
    // phase A: stage buf1 (cc=2t+1), compute buf0 (cc=2t)
    STAGE(BUFU);
    COMPUTE(Xb0, Ab0);
    asm volatile("s_waitcnt vmcnt(0) lgkmcnt(0)" ::: "memory");
    __builtin_amdgcn_s_barrier();
    __builtin_amdgcn_sched_barrier(0);
    // phase B: stage buf0 (cc=2t+2), compute buf1 (cc=2t+1)
    if (t < 15) STAGE(0);
    COMPUTE(Xb1, Ab1);
    asm volatile("s_waitcnt vmcnt(0) lgkmcnt(0)" ::: "memory");
    __builtin_amdgcn_s_barrier();
    __builtin_amdgcn_sched_barrier(0);
  }

  // ---- epilogue: C/D layout col=lane&31, row=(reg&3)+8*(reg>>2)+4*(lane>>5) ----
  const float* scp = scale + b * 512 + ob * 128 + wo * 64;
  float* op = out + (((size_t)(b * 512 + ob * 128 + wo * 64) * 64) +
                     yg * 16 + wyy * 4) * 64 + xg * 32 + ln31;
#pragma unroll
  for (int oh = 0; oh < 2; ++oh) {
#pragma unroll
    for (int ry = 0; ry < 4; ++ry) {
      const f32x16& A = acc[oh * 4 + ry];
#pragma unroll
      for (int reg = 0; reg < 16; ++reg) {
        int orow = (reg & 3) + 8 * (reg >> 2) + hi * 4;
        int ol = oh * 32 + orow;
        op[(size_t)ol * 4096 + ry * 64] = A[reg] * scp[ol];
      }
    }
  }
}

extern "C" void kernel_launch(void* const* d_in, const int* in_sizes, int n_in,
                              void* d_out, int out_size, void* d_ws, size_t ws_size,
                              hipStream_t stream) {
  const float* x     = (const float*)d_in[0];  // [8,512,64,64]
  const float* style = (const float*)d_in[1];  // [8,512]
  const float* w     = (const float*)d_in[2];  // [1,512,512,3,3]
  const float* mw    = (const float*)d_in[3];  // [512,512]
  const float* mb    = (const float*)d_in[4];  // [512]
  float* out = (float*)d_out;

  char* ws = (char*)d_ws;
  float* zp    = (float*)ws;                       // 4 KB zeros
  float* s     = (float*)(ws + 4096);              // 16 KB
  float* scale = (float*)(ws + 20480);             // 16 KB
  float* wsq   = (float*)(ws + 36864);             // 1 MB
  unsigned short* wbf = (unsigned short*)(ws + 1085440);   // 4.72 MB [9][512][512]
  unsigned short* xt  = (unsigned short*)(ws + 5804032);   // 33.5 MB [8][64][64][512]

  k_mod  <<<16,   256, 0, stream>>>(style, mw, mb, s, zp);
  k_wprep<<<1024, 256, 0, stream>>>(w, wsq, wbf);
  k_scale<<<16,   256, 0, stream>>>(wsq, s, scale);
  k_xt   <<<512,  512, 0, stream>>>(x, s, xt);
  k_conv <<<256,  512, 0, stream>>>(xt, wbf, scale, zp, out);
}